// Round 4
// baseline (210.418 us; speedup 1.0000x reference)
//
#include <hip/hip_runtime.h>
#include <hip/hip_bf16.h>

typedef __attribute__((ext_vector_type(4))) float float4v;
typedef __attribute__((ext_vector_type(8))) short short8v;
typedef __attribute__((ext_vector_type(4))) unsigned int uint4v;

__device__ __forceinline__ unsigned short f2bf(float f) {
  __hip_bfloat16 h = __float2bfloat16(f);   // HW RNE cvt
  return __builtin_bit_cast(unsigned short, h);
}
__device__ __forceinline__ unsigned int pk2(float a, float b) {
  return (unsigned int)f2bf(a) | ((unsigned int)f2bf(b) << 16);
}

// td_main: per tile of 4 sampled points (64 rows), gather x=[feat|p_k|0] into
// LDS bf16 [64][104] (K=96), MFMA vs W^T fragments held in regs. The -p_s
// subtraction is deferred: off[m,d] = p_s . Wxyz folded into stats/max.
// knn/spt double-buffered in LDS, prefetched one tile ahead during MFMA.
__global__ __launch_bounds__(256, 6) void td_main(
    const float* __restrict__ point, const float* __restrict__ feat,
    const float* __restrict__ W, const int* __restrict__ sample_idx,
    const int* __restrict__ knn_idx,
    float* __restrict__ ymax_out, float* __restrict__ ymin_out,
    float* __restrict__ partials, int nTiles, int has_ymin)
{
  __shared__ __align__(16) unsigned short A[64 * 104];   // 13312 B
  __shared__ int   knn_lds[2][64];
  __shared__ float spt_lds[2][12];

  const int tid  = threadIdx.x;
  const int lane = tid & 63;
  const int wv   = tid >> 6;        // wave -> output cols wv*32..+31
  const int l15  = lane & 15;
  const int lg   = lane >> 4;

  // One-time: B fragments straight from global W (bf16-rounded), plus the
  // bf16-rounded Wxyz values at this lane's two output channels (for off).
  short8v bfrag[2][3];
  float wx[2][3];
  #pragma unroll
  for (int ni = 0; ni < 2; ++ni) {
    const int d = wv * 32 + ni * 16 + l15;
    #pragma unroll
    for (int kk = 0; kk < 3; ++kk) {
      short8v bf;
      #pragma unroll
      for (int j = 0; j < 8; ++j) {
        int c = kk * 32 + (lg << 3) + j;     // permuted K index
        float v = 0.f;
        if (c < 64)      v = W[(3 + c) * 128 + d];
        else if (c < 67) v = W[(c - 64) * 128 + d];
        bf[j] = (short)f2bf(v);
      }
      bfrag[ni][kk] = bf;
    }
    #pragma unroll
    for (int j = 0; j < 3; ++j) {
      unsigned int ui = (unsigned int)f2bf(W[j * 128 + d]) << 16;
      wx[ni][j] = __builtin_bit_cast(float, ui);
    }
  }

  float sum0 = 0.f, sum1 = 0.f, sq0 = 0.f, sq1 = 0.f;

  // Prologue: stage knn/spt for first tile into buffer 0.
  const int t0 = blockIdx.x;
  if (tid < 64) knn_lds[0][tid] = knn_idx[t0 * 64 + tid];
  if (tid < 12) {
    int pi = tid / 3, c = tid - pi * 3;
    spt_lds[0][tid] = point[(unsigned)sample_idx[t0 * 4 + pi] * 3u + c];
  }
  __syncthreads();

  int b = 0;
  for (int t = t0; t < nTiles; t += gridDim.x, b ^= 1) {
    // (a) issue gathers from knn_lds[b]
    const int grow = knn_lds[b][tid >> 2];
    const int seg  = (tid & 3) << 4;
    const float* src = feat + ((unsigned)grow << 6) + seg;
    float4v f0 = *(const float4v*)(src + 0);
    float4v f1 = *(const float4v*)(src + 4);
    float4v f2 = *(const float4v*)(src + 8);
    float4v f3 = *(const float4v*)(src + 12);
    float px = 0.f, py = 0.f, pz = 0.f;
    if (tid < 64) {
      const float* ps = point + (unsigned)knn_lds[b][tid] * 3u;
      px = ps[0]; py = ps[1]; pz = ps[2];
    }

    // (e) cvt + write A
    {
      uint4v u0, u1;
      u0[0] = pk2(f0[0], f0[1]); u0[1] = pk2(f0[2], f0[3]);
      u0[2] = pk2(f1[0], f1[1]); u0[3] = pk2(f1[2], f1[3]);
      u1[0] = pk2(f2[0], f2[1]); u1[1] = pk2(f2[2], f2[3]);
      u1[2] = pk2(f3[0], f3[1]); u1[3] = pk2(f3[2], f3[3]);
      unsigned short* dst = A + (tid >> 2) * 104 + seg;
      *(short8v*)(dst)     = __builtin_bit_cast(short8v, u0);
      *(short8v*)(dst + 8) = __builtin_bit_cast(short8v, u1);
    }
    if (tid < 64) {
      uint4v u; u[0] = pk2(px, py); u[1] = pk2(pz, 0.f); u[2] = 0u; u[3] = 0u;
      unsigned short* dst = A + tid * 104 + 64;
      *(short8v*)(dst) = __builtin_bit_cast(short8v, u);
      short8v zz = {0, 0, 0, 0, 0, 0, 0, 0};
      *(short8v*)(dst + 8)  = zz;
      *(short8v*)(dst + 16) = zz;
      *(short8v*)(dst + 24) = zz;
    }
    __syncthreads();   // A ready

    // (d) prefetch next tile's knn/spt into the other buffer (hidden by MFMA)
    const int tn = t + gridDim.x;
    if (tn < nTiles) {
      if (tid < 64) knn_lds[b ^ 1][tid] = knn_idx[tn * 64 + tid];
      if (tid < 12) {
        int pi = tid / 3, c = tid - pi * 3;
        spt_lds[b ^ 1][tid] = point[(unsigned)sample_idx[tn * 4 + pi] * 3u + c];
      }
    }

    // (g) MFMA
    float4v acc[4][2];
    #pragma unroll
    for (int mi = 0; mi < 4; ++mi) {
      acc[mi][0] = (float4v){0.f, 0.f, 0.f, 0.f};
      acc[mi][1] = (float4v){0.f, 0.f, 0.f, 0.f};
    }
    #pragma unroll
    for (int mi = 0; mi < 4; ++mi) {
      const unsigned short* ar = A + (mi * 16 + l15) * 104 + (lg << 3);
      short8v a0 = *(const short8v*)(ar);
      short8v a1 = *(const short8v*)(ar + 32);
      short8v a2 = *(const short8v*)(ar + 64);
      #pragma unroll
      for (int ni = 0; ni < 2; ++ni) {
        acc[mi][ni] = __builtin_amdgcn_mfma_f32_16x16x32_bf16(a0, bfrag[ni][0], acc[mi][ni], 0, 0, 0);
        acc[mi][ni] = __builtin_amdgcn_mfma_f32_16x16x32_bf16(a1, bfrag[ni][1], acc[mi][ni], 0, 0, 0);
        acc[mi][ni] = __builtin_amdgcn_mfma_f32_16x16x32_bf16(a2, bfrag[ni][2], acc[mi][ni], 0, 0, 0);
      }
    }

    // (h) stats + per-point max/min, with deferred -off = -p_s.Wxyz
    #pragma unroll
    for (int mi = 0; mi < 4; ++mi) {
      float ps0 = spt_lds[b][mi * 3 + 0];
      float ps1 = spt_lds[b][mi * 3 + 1];
      float ps2 = spt_lds[b][mi * 3 + 2];
      #pragma unroll
      for (int ni = 0; ni < 2; ++ni) {
        float off = fmaf(ps2, wx[ni][2], fmaf(ps1, wx[ni][1], ps0 * wx[ni][0]));
        float4v v = acc[mi][ni];
        float s = (v[0] + v[1]) + (v[2] + v[3]);
        float q = fmaf(v[0], v[0], fmaf(v[1], v[1], fmaf(v[2], v[2], v[3] * v[3])));
        float sadj = fmaf(-4.f, off, s);
        float qadj = fmaf(-off, fmaf(-4.f, off, s + s), q);
        if (ni == 0) { sum0 += sadj; sq0 += qadj; } else { sum1 += sadj; sq1 += qadj; }
        float mx = fmaxf(fmaxf(v[0], v[1]), fmaxf(v[2], v[3])) - off;
        float mn = fminf(fminf(v[0], v[1]), fminf(v[2], v[3])) - off;
        mx = fmaxf(mx, __shfl_xor(mx, 16)); mx = fmaxf(mx, __shfl_xor(mx, 32));
        mn = fminf(mn, __shfl_xor(mn, 16)); mn = fminf(mn, __shfl_xor(mn, 32));
        if (lane < 16) {
          size_t o = (size_t)(t * 4 + mi) * 128 + wv * 32 + ni * 16 + lane;
          ymax_out[o] = mx;
          if (has_ymin) ymin_out[o] = mn;
        }
      }
    }
    __syncthreads();   // A consumed; prefetched knn/spt visible next iter
  }

  // deterministic per-block partials: [block][0..127]=sum, [128..255]=sumsq
  sum0 += __shfl_xor(sum0, 16); sum0 += __shfl_xor(sum0, 32);
  sq0  += __shfl_xor(sq0, 16);  sq0  += __shfl_xor(sq0, 32);
  sum1 += __shfl_xor(sum1, 16); sum1 += __shfl_xor(sum1, 32);
  sq1  += __shfl_xor(sq1, 16);  sq1  += __shfl_xor(sq1, 32);
  if (lane < 16) {
    float* pp = partials + (size_t)blockIdx.x * 256;
    pp[wv * 32 + lane]            = sum0;
    pp[128 + wv * 32 + lane]      = sq0;
    pp[wv * 32 + 16 + lane]       = sum1;
    pp[128 + wv * 32 + 16 + lane] = sq1;
  }
}

// Parallel BN-stats fold: one block per channel.
__global__ __launch_bounds__(256) void td_stats(
    const float* __restrict__ partials,
    const float* __restrict__ gamma,
    const float* __restrict__ beta,
    float* __restrict__ ab, int G, float invN)
{
  __shared__ float ls[256], lq[256];
  const int d = blockIdx.x;
  const int t = threadIdx.x;
  float s = 0.f, q = 0.f;
  for (int g = t; g < G; g += 256) {
    s += partials[(size_t)g * 256 + d];
    q += partials[(size_t)g * 256 + 128 + d];
  }
  ls[t] = s; lq[t] = q;
  __syncthreads();
  for (int w = 128; w > 0; w >>= 1) {
    if (t < w) { ls[t] += ls[t + w]; lq[t] += lq[t + w]; }
    __syncthreads();
  }
  if (t == 0) {
    float mean = ls[0] * invN;
    float var  = fmaxf(lq[0] * invN - mean * mean, 0.f);
    float a = gamma[d] * rsqrtf(var + 1e-5f);
    float bb = beta[d] - mean * a;
    ab[d] = a;
    ab[128 + d] = bb;
  }
}

__global__ __launch_bounds__(256) void td_transform(
    float* __restrict__ outf, const float* __restrict__ ymin,
    const float* __restrict__ ab, int total4, int has_ymin)
{
  __shared__ float sab[256];
  __shared__ int s_anyneg;
  sab[threadIdx.x] = ab[threadIdx.x];
  if (threadIdx.x == 0) s_anyneg = 0;
  __syncthreads();
  if (threadIdx.x < 128 && sab[threadIdx.x] < 0.f) s_anyneg = 1;
  __syncthreads();
  const int need_min = has_ymin && s_anyneg;
  int stride = gridDim.x * blockDim.x;
  for (int i = blockIdx.x * blockDim.x + threadIdx.x; i < total4; i += stride) {
    float4v v = *(const float4v*)(outf + (size_t)i * 4);
    int d0 = (i * 4) & 127;
    if (need_min) {
      float4v mn = *(const float4v*)(ymin + (size_t)i * 4);
      #pragma unroll
      for (int j = 0; j < 4; ++j)
        if (sab[d0 + j] < 0.f) v[j] = mn[j];
    }
    #pragma unroll
    for (int j = 0; j < 4; ++j) {
      float z = fmaf(v[j], sab[d0 + j], sab[128 + d0 + j]);
      v[j] = z > 0.f ? z : 0.f;
    }
    *(float4v*)(outf + (size_t)i * 4) = v;
  }
}

__global__ void td_newpoint(const float* __restrict__ point,
                            const int* __restrict__ sidx,
                            float* __restrict__ out, int m)
{
  int i = blockIdx.x * blockDim.x + threadIdx.x;
  if (i < m) {
    unsigned s = (unsigned)sidx[i];
    out[(size_t)i * 3 + 0] = point[s * 3u + 0];
    out[(size_t)i * 3 + 1] = point[s * 3u + 1];
    out[(size_t)i * 3 + 2] = point[s * 3u + 2];
  }
}

extern "C" void kernel_launch(void* const* d_in, const int* in_sizes, int n_in,
                              void* d_out, int out_size, void* d_ws, size_t ws_size,
                              hipStream_t stream)
{
  const float* point = (const float*)d_in[0];
  const float* feat  = (const float*)d_in[1];
  const float* W     = (const float*)d_in[2];
  const float* gamma = (const float*)d_in[3];
  const float* beta  = (const float*)d_in[4];
  const int* sample_idx = (const int*)d_in[5];
  const int* knn_idx    = (const int*)d_in[6];

  const int m = in_sizes[5];            // 60000
  const int k = in_sizes[6] / m;        // 16
  const int nTiles = m / 4;             // 4 points (64 rows) per tile

  float* out  = (float*)d_out;
  float* newp = out;                    // (m,3)
  float* ymax = out + (size_t)m * 3;    // (m,128) pre-norm max, finished in-place

  // Balanced grid: exactly 8 tiles per block when possible.
  int G = (nTiles + 7) / 8;
  if (G > 2048) G = 2048;
  if (G < 1) G = 1;

  // ws layout: [ab 1KB][partials G*1KB][ymin m*512B if it fits]
  char* ws = (char*)d_ws;
  float* ab = (float*)ws;
  float* partials = (float*)(ws + 1024);
  size_t off_ymin = 1024 + (size_t)G * 1024;
  int has_ymin = (ws_size >= off_ymin + (size_t)m * 512) ? 1 : 0;
  float* ymin = (float*)(ws + off_ymin);

  td_newpoint<<<(m + 255) / 256, 256, 0, stream>>>(point, sample_idx, newp, m);
  td_main<<<G, 256, 0, stream>>>(point, feat, W, sample_idx, knn_idx,
                                 ymax, ymin, partials, nTiles, has_ymin);
  float invN = 1.0f / ((float)m * (float)k);
  td_stats<<<128, 256, 0, stream>>>(partials, gamma, beta, ab, G, invN);
  td_transform<<<2048, 256, 0, stream>>>(ymax, ymin, ab, m * 128 / 4, has_ymin);
}

// Round 5
// 123.884 us; speedup vs baseline: 1.6985x; 1.6985x over previous
//
#include <hip/hip_runtime.h>
#include <hip/hip_bf16.h>

typedef __attribute__((ext_vector_type(4))) float float4v;
typedef __attribute__((ext_vector_type(8))) short short8v;
typedef __attribute__((ext_vector_type(4))) unsigned int uint4v;

__device__ __forceinline__ unsigned short f2bf(float f) {
  __hip_bfloat16 h = __float2bfloat16(f);   // HW RNE cvt
  return __builtin_bit_cast(unsigned short, h);
}
__device__ __forceinline__ unsigned int pk2(float a, float b) {
  return (unsigned int)f2bf(a) | ((unsigned int)f2bf(b) << 16);
}

// td_main: tile = 4 sampled points (64 rows) x K=96 (feat 0..63 | xyz 64..66 | 0).
// Software pipeline: loads for tile t+1 issued into REGISTERS at top of iter t
// (addresses from LDS-double-buffered knn), consumed after the B2 barrier.
// sample_idx -> point chain split across two iterations (no dependent stall).
__global__ __launch_bounds__(256, 4) void td_main(
    const float* __restrict__ point, const float* __restrict__ feat,
    const float* __restrict__ W, const int* __restrict__ sample_idx,
    const int* __restrict__ knn_idx,
    float* __restrict__ ymax_out, float* __restrict__ ymin_out,
    float* __restrict__ partials, int nTiles, int has_ymin)
{
  __shared__ __align__(16) unsigned short smem[128 * 96];  // 24576 B: wt, then A
  __shared__ int knn_lds[2][64];

  unsigned short* wt = smem;        // phase 0: [128][96] bf16 W^T (permuted K)
  unsigned short* A  = smem;        // phase 1+: [64][104] bf16 x-tile

  const int tid  = threadIdx.x;
  const int lane = tid & 63;
  const int wv   = tid >> 6;        // wave -> output channels wv*32..+31
  const int l15  = lane & 15;
  const int lg   = lane >> 4;
  const int G    = gridDim.x;
  const int t0   = blockIdx.x;
  const int seg  = (tid & 3) << 4;  // 16-float segment within a feat row

  // ---------------- prologue ----------------
  for (int i = tid; i < 128 * 96; i += 256) {
    int d = i / 96, c = i - d * 96;
    float v = 0.f;
    if (c < 64)      v = W[(3 + c) * 128 + d];
    else if (c < 67) v = W[(c - 64) * 128 + d];
    wt[i] = f2bf(v);
  }
  const bool alive = (t0 < nTiles);
  if (alive && tid < 64) knn_lds[0][tid] = knn_idx[t0 * 64 + tid];
  __syncthreads();   // wt + knn[0] ready

  short8v bfrag[2][3];
  #pragma unroll
  for (int ni = 0; ni < 2; ++ni)
    #pragma unroll
    for (int kk = 0; kk < 3; ++kk) {
      int row = wv * 32 + ni * 16 + l15;
      int col = kk * 32 + (lg << 3);
      bfrag[ni][kk] = *(const short8v*)&wt[row * 96 + col];
    }

  // pipeline registers
  float4v g0 = {0,0,0,0}, g1 = {0,0,0,0}, g2 = {0,0,0,0}, g3 = {0,0,0,0};
  float qx = 0, qy = 0, qz = 0;   // xyz of this thread's knn row (next tile)
  float sx = 0, sy = 0, sz = 0;   // sampled-point coords (next tile)
  int   si_a = 0;                 // sample idx preloaded one tile further ahead
  int   knn_next = 0;

  // loads for tile t0 (dependent chain once; acceptable in prologue)
  if (alive) {
    const int grow = knn_lds[0][tid >> 2];
    const float* src = feat + ((unsigned)grow << 6) + seg;
    g0 = *(const float4v*)(src);
    g1 = *(const float4v*)(src + 4);
    g2 = *(const float4v*)(src + 8);
    g3 = *(const float4v*)(src + 12);
    if (tid < 64) {
      const float* ps = point + (unsigned)knn_lds[0][tid] * 3u;
      qx = ps[0]; qy = ps[1]; qz = ps[2];
      int si = sample_idx[t0 * 4 + (tid >> 4)];
      const float* pp = point + (unsigned)si * 3u;
      sx = pp[0]; sy = pp[1]; sz = pp[2];
    }
  }
  // stage knn for t0+G; preload si for t0+G
  if (t0 + G < nTiles && tid < 64) {
    knn_lds[1][tid] = knn_idx[(t0 + G) * 64 + tid];
    si_a = sample_idx[(t0 + G) * 4 + (tid >> 4)];
  }
  __syncthreads();   // all bfrag reads done -> safe to overwrite wt with A

  // write A[t0] (full, incl. one-time zero of cols 72..95)
  if (alive) {
    uint4v u0, u1;
    u0[0] = pk2(g0[0], g0[1]); u0[1] = pk2(g0[2], g0[3]);
    u0[2] = pk2(g1[0], g1[1]); u0[3] = pk2(g1[2], g1[3]);
    u1[0] = pk2(g2[0], g2[1]); u1[1] = pk2(g2[2], g2[3]);
    u1[2] = pk2(g3[0], g3[1]); u1[3] = pk2(g3[2], g3[3]);
    unsigned short* dst = A + (tid >> 2) * 104 + seg;
    *(short8v*)(dst)     = __builtin_bit_cast(short8v, u0);
    *(short8v*)(dst + 8) = __builtin_bit_cast(short8v, u1);
    if (tid < 64) {
      uint4v u; u[0] = pk2(qx - sx, qy - sy); u[1] = pk2(qz - sz, 0.f);
      u[2] = 0u; u[3] = 0u;
      unsigned short* dx = A + tid * 104 + 64;
      *(short8v*)(dx) = __builtin_bit_cast(short8v, u);   // cols 64..71
      short8v zz = {0, 0, 0, 0, 0, 0, 0, 0};
      *(short8v*)(dx + 8)  = zz;                          // cols 72..95: once
      *(short8v*)(dx + 16) = zz;
      *(short8v*)(dx + 24) = zz;
    }
  }

  float sum0 = 0.f, sum1 = 0.f, sq0 = 0.f, sq1 = 0.f;

  int b = 0;
  for (int t = t0; t < nTiles; t += G, b ^= 1) {
    __syncthreads();   // B1: A[t] ready; knn[b^1] (tile t+G) visible
    const int tn  = t + G;
    const int tnn = t + 2 * G;
    const bool have_next = (tn < nTiles);

    // issue tile t+1 loads into regs (fly across MFMA + epilogue)
    if (have_next) {
      const int grow = knn_lds[b ^ 1][tid >> 2];
      const float* src = feat + ((unsigned)grow << 6) + seg;
      g0 = *(const float4v*)(src);
      g1 = *(const float4v*)(src + 4);
      g2 = *(const float4v*)(src + 8);
      g3 = *(const float4v*)(src + 12);
      if (tid < 64) {
        const float* ps = point + (unsigned)knn_lds[b ^ 1][tid] * 3u;
        qx = ps[0]; qy = ps[1]; qz = ps[2];
        const float* pp = point + (unsigned)si_a * 3u;  // si_a: loaded last iter
        sx = pp[0]; sy = pp[1]; sz = pp[2];
      }
    }
    // issue tile t+2 index loads (regs; stored to LDS at bottom)
    if (tnn < nTiles && tid < 64) {
      knn_next = knn_idx[tnn * 64 + tid];
      si_a = sample_idx[tnn * 4 + (tid >> 4)];
    }

    // MFMA on A[t]
    float4v acc[4][2];
    #pragma unroll
    for (int mi = 0; mi < 4; ++mi) {
      acc[mi][0] = (float4v){0.f, 0.f, 0.f, 0.f};
      acc[mi][1] = (float4v){0.f, 0.f, 0.f, 0.f};
    }
    #pragma unroll
    for (int mi = 0; mi < 4; ++mi) {
      const unsigned short* ar = A + (mi * 16 + l15) * 104 + (lg << 3);
      short8v a0 = *(const short8v*)(ar);
      short8v a1 = *(const short8v*)(ar + 32);
      short8v a2 = *(const short8v*)(ar + 64);
      #pragma unroll
      for (int ni = 0; ni < 2; ++ni) {
        acc[mi][ni] = __builtin_amdgcn_mfma_f32_16x16x32_bf16(a0, bfrag[ni][0], acc[mi][ni], 0, 0, 0);
        acc[mi][ni] = __builtin_amdgcn_mfma_f32_16x16x32_bf16(a1, bfrag[ni][1], acc[mi][ni], 0, 0, 0);
        acc[mi][ni] = __builtin_amdgcn_mfma_f32_16x16x32_bf16(a2, bfrag[ni][2], acc[mi][ni], 0, 0, 0);
      }
    }

    // epilogue: stats + per-point max/min over k=16
    float mx0[4], mx1[4], mn0[4], mn1[4];
    #pragma unroll
    for (int mi = 0; mi < 4; ++mi) {
      #pragma unroll
      for (int ni = 0; ni < 2; ++ni) {
        float4v v = acc[mi][ni];
        float s = (v[0] + v[1]) + (v[2] + v[3]);
        float q = fmaf(v[0], v[0], fmaf(v[1], v[1], fmaf(v[2], v[2], v[3] * v[3])));
        if (ni == 0) { sum0 += s; sq0 += q; } else { sum1 += s; sq1 += q; }
        float mx = fmaxf(fmaxf(v[0], v[1]), fmaxf(v[2], v[3]));
        float mn = fminf(fminf(v[0], v[1]), fminf(v[2], v[3]));
        mx = fmaxf(mx, __shfl_xor(mx, 16)); mx = fmaxf(mx, __shfl_xor(mx, 32));
        mn = fminf(mn, __shfl_xor(mn, 16)); mn = fminf(mn, __shfl_xor(mn, 32));
        if (ni == 0) { mx0[mi] = mx; mn0[mi] = mn; }
        else         { mx1[mi] = mx; mn1[mi] = mn; }
      }
    }
    // all-64-lane stores: lane group lg writes point t*4+lg (static selects)
    {
      float vx0 = lg == 0 ? mx0[0] : lg == 1 ? mx0[1] : lg == 2 ? mx0[2] : mx0[3];
      float vx1 = lg == 0 ? mx1[0] : lg == 1 ? mx1[1] : lg == 2 ? mx1[2] : mx1[3];
      size_t obase = (size_t)(t * 4 + lg) * 128 + wv * 32 + l15;
      ymax_out[obase]      = vx0;
      ymax_out[obase + 16] = vx1;
      if (has_ymin) {
        float vn0 = lg == 0 ? mn0[0] : lg == 1 ? mn0[1] : lg == 2 ? mn0[2] : mn0[3];
        float vn1 = lg == 0 ? mn1[0] : lg == 1 ? mn1[1] : lg == 2 ? mn1[2] : mn1[3];
        ymin_out[obase]      = vn0;
        ymin_out[obase + 16] = vn1;
      }
    }
    // park prefetched knn for t+2 (loads long completed by now)
    if (tnn < nTiles && tid < 64) knn_lds[b][tid] = knn_next;
    __syncthreads();   // B2: A[t] consumed

    // write A[t+1] from in-flight regs (cols 0..71 only; 72..95 stay zero)
    if (have_next) {
      uint4v u0, u1;
      u0[0] = pk2(g0[0], g0[1]); u0[1] = pk2(g0[2], g0[3]);
      u0[2] = pk2(g1[0], g1[1]); u0[3] = pk2(g1[2], g1[3]);
      u1[0] = pk2(g2[0], g2[1]); u1[1] = pk2(g2[2], g2[3]);
      u1[2] = pk2(g3[0], g3[1]); u1[3] = pk2(g3[2], g3[3]);
      unsigned short* dst = A + (tid >> 2) * 104 + seg;
      *(short8v*)(dst)     = __builtin_bit_cast(short8v, u0);
      *(short8v*)(dst + 8) = __builtin_bit_cast(short8v, u1);
      if (tid < 64) {
        uint4v u; u[0] = pk2(qx - sx, qy - sy); u[1] = pk2(qz - sz, 0.f);
        u[2] = 0u; u[3] = 0u;
        *(short8v*)(A + tid * 104 + 64) = __builtin_bit_cast(short8v, u);
      }
    }
  }

  // deterministic per-block partials: [block][0..127]=sum, [128..255]=sumsq
  sum0 += __shfl_xor(sum0, 16); sum0 += __shfl_xor(sum0, 32);
  sq0  += __shfl_xor(sq0, 16);  sq0  += __shfl_xor(sq0, 32);
  sum1 += __shfl_xor(sum1, 16); sum1 += __shfl_xor(sum1, 32);
  sq1  += __shfl_xor(sq1, 16);  sq1  += __shfl_xor(sq1, 32);
  if (lane < 16) {
    float* pp = partials + (size_t)blockIdx.x * 256;
    pp[wv * 32 + lane]            = sum0;
    pp[128 + wv * 32 + lane]      = sq0;
    pp[wv * 32 + 16 + lane]       = sum1;
    pp[128 + wv * 32 + 16 + lane] = sq1;
  }
}

// Parallel BN-stats fold: one block per channel.
__global__ __launch_bounds__(256) void td_stats(
    const float* __restrict__ partials,
    const float* __restrict__ gamma,
    const float* __restrict__ beta,
    float* __restrict__ ab, int G, float invN)
{
  __shared__ float ls[256], lq[256];
  const int d = blockIdx.x;
  const int t = threadIdx.x;
  float s = 0.f, q = 0.f;
  for (int g = t; g < G; g += 256) {
    s += partials[(size_t)g * 256 + d];
    q += partials[(size_t)g * 256 + 128 + d];
  }
  ls[t] = s; lq[t] = q;
  __syncthreads();
  for (int w = 128; w > 0; w >>= 1) {
    if (t < w) { ls[t] += ls[t + w]; lq[t] += lq[t + w]; }
    __syncthreads();
  }
  if (t == 0) {
    float mean = ls[0] * invN;
    float var  = fmaxf(lq[0] * invN - mean * mean, 0.f);
    float a = gamma[d] * rsqrtf(var + 1e-5f);
    float bb = beta[d] - mean * a;
    ab[d] = a;
    ab[128 + d] = bb;
  }
}

__global__ __launch_bounds__(256) void td_transform(
    float* __restrict__ outf, const float* __restrict__ ymin,
    const float* __restrict__ ab, int total4, int has_ymin)
{
  __shared__ float sab[256];
  __shared__ int s_anyneg;
  sab[threadIdx.x] = ab[threadIdx.x];
  if (threadIdx.x == 0) s_anyneg = 0;
  __syncthreads();
  if (threadIdx.x < 128 && sab[threadIdx.x] < 0.f) s_anyneg = 1;
  __syncthreads();
  const int need_min = has_ymin && s_anyneg;
  int stride = gridDim.x * blockDim.x;
  for (int i = blockIdx.x * blockDim.x + threadIdx.x; i < total4; i += stride) {
    float4v v = *(const float4v*)(outf + (size_t)i * 4);
    int d0 = (i * 4) & 127;
    if (need_min) {
      float4v mn = *(const float4v*)(ymin + (size_t)i * 4);
      #pragma unroll
      for (int j = 0; j < 4; ++j)
        if (sab[d0 + j] < 0.f) v[j] = mn[j];
    }
    #pragma unroll
    for (int j = 0; j < 4; ++j) {
      float z = fmaf(v[j], sab[d0 + j], sab[128 + d0 + j]);
      v[j] = z > 0.f ? z : 0.f;
    }
    *(float4v*)(outf + (size_t)i * 4) = v;
  }
}

__global__ void td_newpoint(const float* __restrict__ point,
                            const int* __restrict__ sidx,
                            float* __restrict__ out, int m)
{
  int i = blockIdx.x * blockDim.x + threadIdx.x;
  if (i < m) {
    unsigned s = (unsigned)sidx[i];
    out[(size_t)i * 3 + 0] = point[s * 3u + 0];
    out[(size_t)i * 3 + 1] = point[s * 3u + 1];
    out[(size_t)i * 3 + 2] = point[s * 3u + 2];
  }
}

extern "C" void kernel_launch(void* const* d_in, const int* in_sizes, int n_in,
                              void* d_out, int out_size, void* d_ws, size_t ws_size,
                              hipStream_t stream)
{
  const float* point = (const float*)d_in[0];
  const float* feat  = (const float*)d_in[1];
  const float* W     = (const float*)d_in[2];
  const float* gamma = (const float*)d_in[3];
  const float* beta  = (const float*)d_in[4];
  const int* sample_idx = (const int*)d_in[5];
  const int* knn_idx    = (const int*)d_in[6];

  const int m = in_sizes[5];            // 60000
  const int k = in_sizes[6] / m;        // 16
  const int nTiles = m / 4;             // 4 points (64 rows) per tile

  float* out  = (float*)d_out;
  float* newp = out;                    // (m,3)
  float* ymax = out + (size_t)m * 3;    // (m,128) pre-norm max, finished in-place

  // Balanced grid: exactly 8 tiles per block when possible.
  int G = (nTiles + 7) / 8;
  if (G > 2048) G = 2048;
  if (G < 1) G = 1;

  // ws layout: [ab 1KB][partials G*1KB][ymin m*512B if it fits]
  char* ws = (char*)d_ws;
  float* ab = (float*)ws;
  float* partials = (float*)(ws + 1024);
  size_t off_ymin = 1024 + (size_t)G * 1024;
  int has_ymin = (ws_size >= off_ymin + (size_t)m * 512) ? 1 : 0;
  float* ymin = (float*)(ws + off_ymin);

  td_newpoint<<<(m + 255) / 256, 256, 0, stream>>>(point, sample_idx, newp, m);
  td_main<<<G, 256, 0, stream>>>(point, feat, W, sample_idx, knn_idx,
                                 ymax, ymin, partials, nTiles, has_ymin);
  float invN = 1.0f / ((float)m * (float)k);
  td_stats<<<128, 256, 0, stream>>>(partials, gamma, beta, ab, G, invN);
  td_transform<<<2048, 256, 0, stream>>>(ymax, ymin, ab, m * 128 / 4, has_ymin);
}

// Round 6
// 88.748 us; speedup vs baseline: 2.3710x; 1.3959x over previous
//
#include <hip/hip_runtime.h>
#include <hip/hip_bf16.h>

typedef __attribute__((ext_vector_type(4))) float float4v;
typedef __attribute__((ext_vector_type(8))) short short8v;
typedef __attribute__((ext_vector_type(4))) unsigned int uint4v;

__device__ __forceinline__ unsigned short f2bf(float f) {
  __hip_bfloat16 h = __float2bfloat16(f);   // HW RNE cvt
  return __builtin_bit_cast(unsigned short, h);
}
__device__ __forceinline__ unsigned int pk2(float a, float b) {
  return (unsigned int)f2bf(a) | ((unsigned int)f2bf(b) << 16);
}

// One-time streaming pass: feat f32 -> bf16 table (halves gather bytes).
__global__ __launch_bounds__(256) void td_prep(const float* __restrict__ feat,
                                               unsigned short* __restrict__ fb,
                                               int total8) {
  int i = blockIdx.x * blockDim.x + threadIdx.x;
  if (i < total8) {
    const float4v a = *(const float4v*)(feat + (size_t)i * 8);
    const float4v c = *(const float4v*)(feat + (size_t)i * 8 + 4);
    uint4v u;
    u[0] = pk2(a[0], a[1]); u[1] = pk2(a[2], a[3]);
    u[2] = pk2(c[0], c[1]); u[3] = pk2(c[2], c[3]);
    *(uint4v*)(fb + (size_t)i * 8) = u;
  }
}

// td_main: tile = 4 sampled points (64 rows) x K=96 (feat 0..63 | xyz 64..66 | 0).
// Register software-pipeline: tile t+1's gathers issued at top of iter t from
// the bf16 table, parked in regs across MFMA+epilogue, written to LDS after B2.
__global__ __launch_bounds__(256, 4) void td_main(
    const float* __restrict__ point, const float* __restrict__ feat,
    const unsigned short* __restrict__ fb, const float* __restrict__ W,
    const float* __restrict__ gamma,
    const int* __restrict__ sample_idx, const int* __restrict__ knn_idx,
    float* __restrict__ ymax_out, float* __restrict__ ymin_out,
    float* __restrict__ partials, int nTiles, int has_ymin, int use_fb)
{
  __shared__ __align__(16) unsigned short A[64 * 104];   // 13312 B
  __shared__ int knn_lds[2][64];

  const int tid  = threadIdx.x;
  const int lane = tid & 63;
  const int wv   = tid >> 6;        // wave -> output channels wv*32..+31
  const int l15  = lane & 15;
  const int lg   = lane >> 4;
  const int G    = gridDim.x;
  const int t0   = blockIdx.x;
  const int segs = (tid & 3) << 4;  // element offset of this thread's 16-elem segment

  // One-time: B fragments direct from global W (bf16-rounded), permuted K.
  short8v bfrag[2][3];
  #pragma unroll
  for (int ni = 0; ni < 2; ++ni) {
    const int d = wv * 32 + ni * 16 + l15;
    #pragma unroll
    for (int kk = 0; kk < 3; ++kk) {
      short8v bf;
      #pragma unroll
      for (int j = 0; j < 8; ++j) {
        int c = kk * 32 + (lg << 3) + j;
        float v = 0.f;
        if (c < 64)      v = W[(3 + c) * 128 + d];
        else if (c < 67) v = W[(c - 64) * 128 + d];
        bf[j] = (short)f2bf(v);
      }
      bfrag[ni][kk] = bf;
    }
  }
  // min-path only needed for channels with gamma<0 (sign(a)==sign(gamma))
  const float gva = gamma[wv * 32 + l15];
  const float gvb = gamma[wv * 32 + 16 + l15];
  const bool  do_min = has_ymin && (__ballot((gva < 0.f) || (gvb < 0.f)) != 0ull);

  const bool alive = (t0 < nTiles);
  if (alive && tid < 64) knn_lds[0][tid] = knn_idx[t0 * 64 + tid];
  __syncthreads();

  // pipeline registers
  uint4v h0 = {0,0,0,0}, h1 = {0,0,0,0};
  float qx = 0, qy = 0, qz = 0, sx = 0, sy = 0, sz = 0;
  int   si_a = 0, knn_next = 0;

  // tile t0 loads (dependent chain once, in prologue)
  if (alive) {
    const int grow = knn_lds[0][tid >> 2];
    if (use_fb) {
      const uint4v* src = (const uint4v*)(fb + ((size_t)grow << 6) + segs);
      h0 = src[0]; h1 = src[1];
    } else {
      const float* srcf = feat + ((size_t)grow << 6) + segs;
      float4v f0 = *(const float4v*)(srcf),     f1 = *(const float4v*)(srcf + 4);
      float4v f2 = *(const float4v*)(srcf + 8), f3 = *(const float4v*)(srcf + 12);
      h0[0] = pk2(f0[0], f0[1]); h0[1] = pk2(f0[2], f0[3]);
      h0[2] = pk2(f1[0], f1[1]); h0[3] = pk2(f1[2], f1[3]);
      h1[0] = pk2(f2[0], f2[1]); h1[1] = pk2(f2[2], f2[3]);
      h1[2] = pk2(f3[0], f3[1]); h1[3] = pk2(f3[2], f3[3]);
    }
    if (tid < 64) {
      const float* ps = point + (unsigned)knn_lds[0][tid] * 3u;
      qx = ps[0]; qy = ps[1]; qz = ps[2];
      int si = sample_idx[t0 * 4 + (tid >> 4)];
      const float* pp2 = point + (unsigned)si * 3u;
      sx = pp2[0]; sy = pp2[1]; sz = pp2[2];
    }
  }
  if (t0 + G < nTiles && tid < 64) {
    knn_lds[1][tid] = knn_idx[(t0 + G) * 64 + tid];
    si_a = sample_idx[(t0 + G) * 4 + (tid >> 4)];
  }

  // write A[t0] (incl. one-time zero of cols 72..95)
  if (alive) {
    unsigned short* dst = A + (tid >> 2) * 104 + segs;
    *(uint4v*)(dst)     = h0;
    *(uint4v*)(dst + 8) = h1;
    if (tid < 64) {
      uint4v u; u[0] = pk2(qx - sx, qy - sy); u[1] = pk2(qz - sz, 0.f);
      u[2] = 0u; u[3] = 0u;
      unsigned short* dx = A + tid * 104 + 64;
      *(uint4v*)(dx) = u;                         // cols 64..71
      uint4v zz = {0u, 0u, 0u, 0u};
      *(uint4v*)(dx + 8)  = zz;                   // cols 72..95: once
      *(uint4v*)(dx + 16) = zz;
      *(uint4v*)(dx + 24) = zz;
    }
  }

  float sum0 = 0.f, sum1 = 0.f, sq0 = 0.f, sq1 = 0.f;

  int b = 0;
  for (int t = t0; t < nTiles; t += G, b ^= 1) {
    __syncthreads();   // B1: A[t] ready; knn[b^1] (tile t+G) visible
    const int tn  = t + G;
    const int tnn = t + 2 * G;
    const bool have_next = (tn < nTiles);

    // issue tile t+1 loads into regs (fly across MFMA + epilogue)
    if (have_next) {
      const int grow = knn_lds[b ^ 1][tid >> 2];
      if (use_fb) {
        const uint4v* src = (const uint4v*)(fb + ((size_t)grow << 6) + segs);
        h0 = src[0]; h1 = src[1];
      } else {
        const float* srcf = feat + ((size_t)grow << 6) + segs;
        float4v f0 = *(const float4v*)(srcf),     f1 = *(const float4v*)(srcf + 4);
        float4v f2 = *(const float4v*)(srcf + 8), f3 = *(const float4v*)(srcf + 12);
        h0[0] = pk2(f0[0], f0[1]); h0[1] = pk2(f0[2], f0[3]);
        h0[2] = pk2(f1[0], f1[1]); h0[3] = pk2(f1[2], f1[3]);
        h1[0] = pk2(f2[0], f2[1]); h1[1] = pk2(f2[2], f2[3]);
        h1[2] = pk2(f3[0], f3[1]); h1[3] = pk2(f3[2], f3[3]);
      }
      if (tid < 64) {
        const float* ps = point + (unsigned)knn_lds[b ^ 1][tid] * 3u;
        qx = ps[0]; qy = ps[1]; qz = ps[2];
        const float* pp2 = point + (unsigned)si_a * 3u;  // si_a from last iter
        sx = pp2[0]; sy = pp2[1]; sz = pp2[2];
      }
    }
    // issue tile t+2 index loads
    if (tnn < nTiles && tid < 64) {
      knn_next = knn_idx[tnn * 64 + tid];
      si_a = sample_idx[tnn * 4 + (tid >> 4)];
    }

    // MFMA on A[t]
    float4v acc[4][2];
    #pragma unroll
    for (int mi = 0; mi < 4; ++mi) {
      acc[mi][0] = (float4v){0.f, 0.f, 0.f, 0.f};
      acc[mi][1] = (float4v){0.f, 0.f, 0.f, 0.f};
    }
    #pragma unroll
    for (int mi = 0; mi < 4; ++mi) {
      const unsigned short* ar = A + (mi * 16 + l15) * 104 + (lg << 3);
      short8v a0 = *(const short8v*)(ar);
      short8v a1 = *(const short8v*)(ar + 32);
      short8v a2 = *(const short8v*)(ar + 64);
      #pragma unroll
      for (int ni = 0; ni < 2; ++ni) {
        acc[mi][ni] = __builtin_amdgcn_mfma_f32_16x16x32_bf16(a0, bfrag[ni][0], acc[mi][ni], 0, 0, 0);
        acc[mi][ni] = __builtin_amdgcn_mfma_f32_16x16x32_bf16(a1, bfrag[ni][1], acc[mi][ni], 0, 0, 0);
        acc[mi][ni] = __builtin_amdgcn_mfma_f32_16x16x32_bf16(a2, bfrag[ni][2], acc[mi][ni], 0, 0, 0);
      }
    }

    // epilogue: stats + per-point max (min only if some gamma<0)
    float mx0[4], mx1[4], mn0[4], mn1[4];
    #pragma unroll
    for (int mi = 0; mi < 4; ++mi) {
      #pragma unroll
      for (int ni = 0; ni < 2; ++ni) {
        float4v v = acc[mi][ni];
        float s = (v[0] + v[1]) + (v[2] + v[3]);
        float q = fmaf(v[0], v[0], fmaf(v[1], v[1], fmaf(v[2], v[2], v[3] * v[3])));
        if (ni == 0) { sum0 += s; sq0 += q; } else { sum1 += s; sq1 += q; }
        float mx = fmaxf(fmaxf(v[0], v[1]), fmaxf(v[2], v[3]));
        mx = fmaxf(mx, __shfl_xor(mx, 16)); mx = fmaxf(mx, __shfl_xor(mx, 32));
        if (ni == 0) mx0[mi] = mx; else mx1[mi] = mx;
        if (do_min) {
          float mn = fminf(fminf(v[0], v[1]), fminf(v[2], v[3]));
          mn = fminf(mn, __shfl_xor(mn, 16)); mn = fminf(mn, __shfl_xor(mn, 32));
          if (ni == 0) mn0[mi] = mn; else mn1[mi] = mn;
        }
      }
    }
    {
      float vx0 = lg == 0 ? mx0[0] : lg == 1 ? mx0[1] : lg == 2 ? mx0[2] : mx0[3];
      float vx1 = lg == 0 ? mx1[0] : lg == 1 ? mx1[1] : lg == 2 ? mx1[2] : mx1[3];
      size_t obase = (size_t)(t * 4 + lg) * 128 + wv * 32 + l15;
      ymax_out[obase]      = vx0;
      ymax_out[obase + 16] = vx1;
      if (do_min) {
        float vn0 = lg == 0 ? mn0[0] : lg == 1 ? mn0[1] : lg == 2 ? mn0[2] : mn0[3];
        float vn1 = lg == 0 ? mn1[0] : lg == 1 ? mn1[1] : lg == 2 ? mn1[2] : mn1[3];
        if (gva < 0.f) ymin_out[obase]      = vn0;
        if (gvb < 0.f) ymin_out[obase + 16] = vn1;
      }
    }
    // park prefetched knn for t+2 (loads long completed)
    if (tnn < nTiles && tid < 64) knn_lds[b][tid] = knn_next;
    __syncthreads();   // B2: A[t] consumed

    // write A[t+1] from in-flight regs (cols 0..71; 72..95 stay zero)
    if (have_next) {
      unsigned short* dst = A + (tid >> 2) * 104 + segs;
      *(uint4v*)(dst)     = h0;
      *(uint4v*)(dst + 8) = h1;
      if (tid < 64) {
        uint4v u; u[0] = pk2(qx - sx, qy - sy); u[1] = pk2(qz - sz, 0.f);
        u[2] = 0u; u[3] = 0u;
        *(uint4v*)(A + tid * 104 + 64) = u;
      }
    }
  }

  // deterministic per-block partials
  sum0 += __shfl_xor(sum0, 16); sum0 += __shfl_xor(sum0, 32);
  sq0  += __shfl_xor(sq0, 16);  sq0  += __shfl_xor(sq0, 32);
  sum1 += __shfl_xor(sum1, 16); sum1 += __shfl_xor(sum1, 32);
  sq1  += __shfl_xor(sq1, 16);  sq1  += __shfl_xor(sq1, 32);
  if (lane < 16) {
    float* pp = partials + (size_t)blockIdx.x * 256;
    pp[wv * 32 + lane]            = sum0;
    pp[128 + wv * 32 + lane]      = sq0;
    pp[wv * 32 + 16 + lane]       = sum1;
    pp[128 + wv * 32 + 16 + lane] = sq1;
  }
}

// Parallel BN-stats fold: one block per channel.
__global__ __launch_bounds__(256) void td_stats(
    const float* __restrict__ partials,
    const float* __restrict__ gamma,
    const float* __restrict__ beta,
    float* __restrict__ ab, int G, float invN)
{
  __shared__ float ls[256], lq[256];
  const int d = blockIdx.x;
  const int t = threadIdx.x;
  float s = 0.f, q = 0.f;
  for (int g = t; g < G; g += 256) {
    s += partials[(size_t)g * 256 + d];
    q += partials[(size_t)g * 256 + 128 + d];
  }
  ls[t] = s; lq[t] = q;
  __syncthreads();
  for (int w = 128; w > 0; w >>= 1) {
    if (t < w) { ls[t] += ls[t + w]; lq[t] += lq[t + w]; }
    __syncthreads();
  }
  if (t == 0) {
    float mean = ls[0] * invN;
    float var  = fmaxf(lq[0] * invN - mean * mean, 0.f);
    float a = gamma[d] * rsqrtf(var + 1e-5f);
    float bb = beta[d] - mean * a;
    ab[d] = a;
    ab[128 + d] = bb;
  }
}

__global__ __launch_bounds__(256) void td_transform(
    float* __restrict__ outf, const float* __restrict__ ymin,
    const float* __restrict__ ab, int total4, int has_ymin)
{
  __shared__ float sab[256];
  __shared__ int s_anyneg;
  sab[threadIdx.x] = ab[threadIdx.x];
  if (threadIdx.x == 0) s_anyneg = 0;
  __syncthreads();
  if (threadIdx.x < 128 && sab[threadIdx.x] < 0.f) s_anyneg = 1;
  __syncthreads();
  const int need_min = has_ymin && s_anyneg;
  int stride = gridDim.x * blockDim.x;
  for (int i = blockIdx.x * blockDim.x + threadIdx.x; i < total4; i += stride) {
    float4v v = *(const float4v*)(outf + (size_t)i * 4);
    int d0 = (i * 4) & 127;
    if (need_min) {
      float4v mn = *(const float4v*)(ymin + (size_t)i * 4);
      #pragma unroll
      for (int j = 0; j < 4; ++j)
        if (sab[d0 + j] < 0.f) v[j] = mn[j];
    }
    #pragma unroll
    for (int j = 0; j < 4; ++j) {
      float z = fmaf(v[j], sab[d0 + j], sab[128 + d0 + j]);
      v[j] = z > 0.f ? z : 0.f;
    }
    *(float4v*)(outf + (size_t)i * 4) = v;
  }
}

__global__ void td_newpoint(const float* __restrict__ point,
                            const int* __restrict__ sidx,
                            float* __restrict__ out, int m)
{
  int i = blockIdx.x * blockDim.x + threadIdx.x;
  if (i < m) {
    unsigned s = (unsigned)sidx[i];
    out[(size_t)i * 3 + 0] = point[s * 3u + 0];
    out[(size_t)i * 3 + 1] = point[s * 3u + 1];
    out[(size_t)i * 3 + 2] = point[s * 3u + 2];
  }
}

extern "C" void kernel_launch(void* const* d_in, const int* in_sizes, int n_in,
                              void* d_out, int out_size, void* d_ws, size_t ws_size,
                              hipStream_t stream)
{
  const float* point = (const float*)d_in[0];
  const float* feat  = (const float*)d_in[1];
  const float* W     = (const float*)d_in[2];
  const float* gamma = (const float*)d_in[3];
  const float* beta  = (const float*)d_in[4];
  const int* sample_idx = (const int*)d_in[5];
  const int* knn_idx    = (const int*)d_in[6];

  const int m = in_sizes[5];            // 60000
  const int k = in_sizes[6] / m;        // 16
  const int nTiles = m / 4;             // 4 points (64 rows) per tile
  const int feat_elems = in_sizes[1];   // n * 64

  float* out  = (float*)d_out;
  float* newp = out;                    // (m,3)
  float* ymax = out + (size_t)m * 3;    // (m,128) pre-norm max, finished in-place

  int G = (nTiles + 7) / 8;             // 8 tiles per block
  if (G > 2048) G = 2048;
  if (G < 1) G = 1;

  // ws layout: [ab 1KB][partials G*1KB][feat_bf16][ymin if it fits]
  char* ws = (char*)d_ws;
  float* ab = (float*)ws;
  float* partials = (float*)(ws + 1024);
  size_t fb_off = 1024 + (size_t)G * 1024;
  size_t fb_bytes = (size_t)feat_elems * 2;
  int use_fb = (ws_size >= fb_off + fb_bytes) ? 1 : 0;
  unsigned short* fb = (unsigned short*)(ws + fb_off);
  size_t ymin_off = fb_off + (use_fb ? fb_bytes : 0);
  int has_ymin = (ws_size >= ymin_off + (size_t)m * 512) ? 1 : 0;
  float* ymin = (float*)(ws + ymin_off);

  if (use_fb) {
    int total8 = feat_elems / 8;
    td_prep<<<(total8 + 255) / 256, 256, 0, stream>>>(feat, fb, total8);
  }
  td_newpoint<<<(m + 255) / 256, 256, 0, stream>>>(point, sample_idx, newp, m);
  td_main<<<G, 256, 0, stream>>>(point, feat, fb, W, gamma, sample_idx, knn_idx,
                                 ymax, ymin, partials, nTiles, has_ymin, use_fb);
  float invN = 1.0f / ((float)m * (float)k);
  td_stats<<<128, 256, 0, stream>>>(partials, gamma, beta, ab, G, invN);
  td_transform<<<2048, 256, 0, stream>>>(ymax, ymin, ab, m * 128 / 4, has_ymin);
}